// Round 1
// baseline (174.248 us; speedup 1.0000x reference)
//
#include <hip/hip_runtime.h>
#include <math.h>

#define NTH 256

typedef float v4f __attribute__((ext_vector_type(4)));

// ============ workspace float offsets ============
// Final tables (read wave-uniform by actor_main): 1940 floats = 485 float4
// (WQ0 / M / TB pre-scaled by 1/sqrt(32) — actor logits skip the scale mul)
enum : int {
  WQ0_OFF = 0,        // [4][19][8]  = 608
  M_OFF   = 608,      // [36][32]    = 1152   (AO0 @ WQ1fold, pre-scaled)
  TB_OFF  = 1760,     // [4][8]      = 32     (B0 @ WQ1fold, pre-scaled)
  AO1_OFF = 1792,     // [36][4]     = 144
  B1H_OFF = 1936,     // [4]         = 4
  TBL_N   = 1940,
  PREF_SCRATCH = 4096 // prefetch keep-alive sums live here (dead data)
};

// ---------------- prep_fused: ONE kernel, every block self-contained ----------------
// Reassociated algebra removes all cross-block dependencies:
//   M[t][h2,j2]  = sum_d wb1[h2,j2,d] * G[t][h2,d],  G = AO0[t] @ wq1       (was AO0 @ WQ1)
//   AO1[t1][o]   = sum_j headw[j,o]   * R[t1][j],    R = P1[t1] @ fpw1part  (was P1 @ F1T/F1B)
//   TB[h,j]      = sum_d wb1[h,j,d]   * Gb[h,d],     Gb = B0 @ wq1
// Blocks:  0..35  M rows        36..71  AO1 rows      72 TB      73 B1H
//          74..76 WQ0           77..511 obs->L3 prefetch (overlaps prep compute)
__global__ __launch_bounds__(NTH) void prep_fused(
    const float* __restrict__ wq0,  const float* __restrict__ wak0, const float* __restrict__ wok0,
    const float* __restrict__ wav0, const float* __restrict__ wov0,
    const float* __restrict__ apw0, const float* __restrict__ opw0,
    const float* __restrict__ fpw0, const float* __restrict__ fpb0,
    const float* __restrict__ apb0, const float* __restrict__ opb0,
    const float* __restrict__ wq1,  const float* __restrict__ wak1, const float* __restrict__ wok1,
    const float* __restrict__ wav1, const float* __restrict__ wov1,
    const float* __restrict__ apw1, const float* __restrict__ opw1,
    const float* __restrict__ fpw1, const float* __restrict__ fpb1,
    const float* __restrict__ apb1, const float* __restrict__ opb1,
    const float* __restrict__ headw, const float* __restrict__ headb,
    const float* __restrict__ obs, float* __restrict__ ws, int n)
{
  const int b = blockIdx.x;
  const int tid = threadIdx.x;
  const float scale = 0.17677669529663687f;   // 1/sqrt(32)
  __shared__ float sm[768];

  if (b < 36) {
    // ---- M row t:  P(128) -> AO0(128) -> G(512) -> M(32) ----
    const int t = b, h0 = t / 9, i0 = t % 9;
    float* sP = sm; float* sA = sm + 128; float* sG = sm + 256;
    if (tid < 128) {
      const float* w  = (i0 < 7 ? wav0 + i0 * 512 : wov0 + (i0 - 7) * 512) + h0 * 128;
      const float* pw = (i0 < 7 ? apw0 : opw0) + (h0 * 128) * 128 + tid;
      float acc = 0.f;
#pragma unroll 4
      for (int c = 0; c < 128; c++) acc += w[c] * pw[c * 128];
      sP[tid] = acc;
    }
    __syncthreads();
    if (tid < 128) {
      const float* f = fpw0 + (i0 < 7 ? 0 : 128 * 128) + tid;
      float acc = 0.f;
#pragma unroll 4
      for (int u = 0; u < 128; u++) acc += sP[u] * f[u * 128];
      sA[tid] = acc;
    }
    __syncthreads();
#pragma unroll
    for (int rep = 0; rep < 2; rep++) {
      const int hd = tid + rep * 256;
      float acc = 0.f;
#pragma unroll 4
      for (int c = 0; c < 128; c++) acc += sA[c] * wq1[c * 512 + hd];
      sG[hd] = acc;
    }
    __syncthreads();
    if (tid < 32) {
      const int h2 = tid >> 3, j2 = tid & 7;
      const float* wb = (j2 < 6 ? wak1 + j2 * 512 : wok1 + (j2 - 6) * 512) + h2 * 128;
      const float* g = sG + h2 * 128;
      float acc = 0.f;
#pragma unroll 4
      for (int d = 0; d < 128; d++) acc += g[d] * wb[d];
      ws[M_OFF + t * 32 + tid] = acc * scale;
    }
  } else if (b < 72) {
    // ---- AO1 row t1:  P1(128) -> R(128) -> AO1(4) ----
    const int t1 = b - 36, h = t1 / 9, i = t1 % 9;
    float* sP = sm; float* sR = sm + 128;
    if (tid < 128) {
      const float* w  = (i < 7 ? wav1 + i * 512 : wov1 + (i - 7) * 512) + h * 128;
      const float* pw = (i < 7 ? apw1 : opw1) + (h * 128) * 128 + tid;
      float acc = 0.f;
#pragma unroll 4
      for (int c = 0; c < 128; c++) acc += w[c] * pw[c * 128];
      sP[tid] = acc;
    }
    __syncthreads();
    if (tid < 128) {
      const float* f = fpw1 + (i < 7 ? 0 : 128 * 128) + tid;
      float acc = 0.f;
#pragma unroll 4
      for (int u = 0; u < 128; u++) acc += sP[u] * f[u * 128];
      sR[tid] = acc;
    }
    __syncthreads();
    if (tid < 4) {
      float acc = 0.f;
#pragma unroll 4
      for (int j = 0; j < 128; j++) acc += sR[j] * headw[j * 4 + tid];
      ws[AO1_OFF + t1 * 4 + tid] = acc;
    }
  } else if (b == 72) {
    // ---- TB:  B0(128) -> Gb(512) -> TB(32) ----
    float* sB = sm; float* sG = sm + 256;
    if (tid < 128) {
      float acc = fpb0[tid];
#pragma unroll 4
      for (int c = 0; c < 128; c++)
        acc += apb0[c] * fpw0[c * 128 + tid] + opb0[c] * fpw0[(128 + c) * 128 + tid];
      sB[tid] = acc;
    }
    __syncthreads();
#pragma unroll
    for (int rep = 0; rep < 2; rep++) {
      const int hd = tid + rep * 256;
      float acc = 0.f;
#pragma unroll 4
      for (int cc = 0; cc < 128; cc++) acc += sB[cc] * wq1[cc * 512 + hd];
      sG[hd] = acc;
    }
    __syncthreads();
    if (tid < 32) {
      const int h = tid >> 3, j = tid & 7;
      const float* wb = (j < 6 ? wak1 + j * 512 : wok1 + (j - 6) * 512) + h * 128;
      const float* g = sG + h * 128;
      float acc = 0.f;
#pragma unroll 4
      for (int d = 0; d < 128; d++) acc += g[d] * wb[d];
      ws[TB_OFF + tid] = acc * scale;
    }
  } else if (b == 73) {
    // ---- B1H:  BB1(128) -> B1H(4) ----
    float* sB = sm;
    if (tid < 128) {
      float acc = fpb1[tid];
#pragma unroll 4
      for (int c = 0; c < 128; c++)
        acc += apb1[c] * fpw1[c * 128 + tid] + opb1[c] * fpw1[(128 + c) * 128 + tid];
      sB[tid] = acc;
    }
    __syncthreads();
    if (tid < 4) {
      float acc = headb[tid];
#pragma unroll 4
      for (int j = 0; j < 128; j++) acc += sB[j] * headw[j * 4 + tid];
      ws[B1H_OFF + tid] = acc;
    }
  } else if (b < 77) {
    // ---- WQ0[h][r][j] (608 entries, v4f dot over c) ----
    const int idx = (b - 74) * NTH + tid;
    if (idx < 608) {
      const int j = idx & 7, r = (idx >> 3) % 19, h = idx / 152;
      const v4f* a4 = (const v4f*)(wq0 + r * 512 + h * 128);
      const v4f* b4 = (const v4f*)((j < 6 ? wak0 + j * 512 : wok0 + (j - 6) * 512) + h * 128);
      v4f va = (v4f)0.f;
#pragma unroll 8
      for (int c = 0; c < 32; c++) va += a4[c] * b4[c];
      ws[WQ0_OFF + idx] = (va[0] + va[1] + va[2] + va[3]) * scale;
    }
  } else {
    // ---- obs -> L3 warm: one dword per 128-B line, overlapped with prep ----
    const int pid = (b - 77) * NTH + tid;
    const size_t total = (size_t)n * 37;
    float s = 0.f;
    for (size_t p = (size_t)pid * 32; p < total; p += (size_t)(512 - 77) * NTH * 32)
      s += obs[p];
    ws[PREF_SCRATCH + pid] = s;   // keep-alive store into dead scratch
  }
}

// ---------------- main: 1 thread/sample; coalesced obs via LDS stage ----------------
__global__ __launch_bounds__(NTH) void actor_main(
    const float* __restrict__ obs, const float* __restrict__ ws,
    const float* __restrict__ pca0, const float* __restrict__ pco0,
    const float* __restrict__ pca1, const float* __restrict__ pco1,
    float* __restrict__ out, int n)
{
  const int tid = threadIdx.x;
  const int gid = blockIdx.x * NTH + tid;

  // ---- coalesced stage: 2368 float4 per block (256*37 floats), then
  //      per-thread reads at stride 37 (37 mod 32 = 5, coprime -> conflict-free)
  __shared__ v4f sObsV[NTH * 37 / 4];
  float* sObs = (float*)sObsV;
  {
    const size_t total_f = (size_t)n * 37;
    const size_t v4base = (size_t)blockIdx.x * (NTH * 37 / 4);
    const v4f* src = (const v4f*)obs;
#pragma unroll
    for (int k = 0; k < 9; k++) {
      const size_t vi = v4base + k * NTH + tid;
      if (vi * 4 + 4 <= total_f) {
        sObsV[k * NTH + tid] = src[vi];
      } else {
#pragma unroll
        for (int e = 0; e < 4; e++) {
          const size_t f = vi * 4 + e;
          if (f < total_f) sObs[(k * NTH + tid) * 4 + e] = obs[f];
        }
      }
    }
    if (tid < 64) {
      const size_t vi = v4base + 9 * NTH + tid;
      if (vi * 4 + 4 <= total_f) {
        sObsV[9 * NTH + tid] = src[vi];
      } else {
#pragma unroll
        for (int e = 0; e < 4; e++) {
          const size_t f = vi * 4 + e;
          if (f < total_f) sObs[(9 * NTH + tid) * 4 + e] = obs[f];
        }
      }
    }
  }
  __syncthreads();
  if (gid >= n) return;

  // All tbl[] indices below are compile-time constants -> wave-uniform
  // addresses -> scalar-pipe s_load; table (7.8 KB) stays K$-resident.
  const v4f* __restrict__ tbl = (const v4f*)ws;

  // ---- per-lane obs from LDS ----
  float o[37];
#pragma unroll
  for (int i = 0; i < 37; i++) o[i] = sObs[tid * 37 + i];

  // ---- unpack features ----
  float qf[19];
#pragma unroll
  for (int i = 0; i < 12; i++) qf[i] = o[i];
#pragma unroll
  for (int i = 0; i < 7; i++) qf[12 + i] = o[30 + i];
  float nb[2][6];
#pragma unroll
  for (int k2 = 0; k2 < 2; k2++)
#pragma unroll
    for (int i = 0; i < 6; i++) nb[k2][i] = o[12 + 6 * k2 + i];
  const float nbv6[2] = { o[24], o[25] };
  const float obf[2][2] = { { o[26], o[27] }, { o[28], o[29] } };
  const float ax = o[0], ay = o[1];

  // ---- distances & decay weights ----
  float dista[2], disto[2];
#pragma unroll
  for (int k2 = 0; k2 < 2; k2++) {
    float dx = ax - nb[k2][0], dy = ay - nb[k2][1];
    dista[k2] = sqrtf(dx * dx + dy * dy);
    float ex = ax - obf[k2][0], ey = ay - obf[k2][1];
    disto[k2] = sqrtf(ex * ex + ey * ey);
  }
  const float ca0 = pca0[0], co0 = pco0[0], ca1 = pca1[0], co1 = pco1[0];
  float dwa0[2], dwo0[2], dwa1[2], dwo1[2];
#pragma unroll
  for (int k2 = 0; k2 < 2; k2++) {
    dwa0[k2] = __expf(-ca0 * dista[k2]);
    dwo0[k2] = __expf(-co0 * disto[k2]);
    dwa1[k2] = __expf(-ca1 * dista[k2]);
    dwo1[k2] = __expf(-co1 * disto[k2]);
  }

  // ---- layer 0 query fold: t0v[h*2+half] (packed, pre-scaled tables) ----
  v4f t0v[8];
#pragma unroll
  for (int z = 0; z < 8; z++) t0v[z] = (v4f)0.f;
#pragma unroll
  for (int h = 0; h < 4; h++) {
#pragma unroll
    for (int r = 0; r < 19; r++) {
      float q = qf[r];
      t0v[h * 2 + 0] += tbl[(h * 19 + r) * 2 + 0] * q;
      t0v[h * 2 + 1] += tbl[(h * 19 + r) * 2 + 1] * q;
    }
  }

  // ---- layer 0 attention -> weighted features wff[36] (t = h*9+i) ----
  float wff[36];
#pragma unroll
  for (int h = 0; h < 4; h++) {
    float la[2], lo[2];
#pragma unroll
    for (int k2 = 0; k2 < 2; k2++) {
      float da = t0v[h*2][0]*nb[k2][0] + t0v[h*2][1]*nb[k2][1] + t0v[h*2][2]*nb[k2][2]
               + t0v[h*2][3]*nb[k2][3] + t0v[h*2+1][0]*nb[k2][4] + t0v[h*2+1][1]*nb[k2][5];
      la[k2] = da * dwa0[k2];
      float dof = t0v[h*2+1][2]*obf[k2][0] + t0v[h*2+1][3]*obf[k2][1];
      lo[k2] = dof * dwo0[k2];
    }
    float e  = __expf(la[1] - la[0]); float aa1 = e  / (1.f + e);  float aa0 = 1.f - aa1;
    float eo = __expf(lo[1] - lo[0]); float bo1 = eo / (1.f + eo); float bo0 = 1.f - bo1;
#pragma unroll
    for (int i = 0; i < 6; i++) wff[h * 9 + i] = aa0 * nb[0][i] + aa1 * nb[1][i];
    wff[h * 9 + 6] = aa0 * nbv6[0] + aa1 * nbv6[1];
    wff[h * 9 + 7] = bo0 * obf[0][0] + bo1 * obf[1][0];
    wff[h * 9 + 8] = bo0 * obf[0][1] + bo1 * obf[1][1];
  }

  // ---- layer 1 query fold via M: t1v = TB + wff @ M (packed, pre-scaled) ----
  v4f t1v[8];
#pragma unroll
  for (int q = 0; q < 8; q++) t1v[q] = tbl[440 + q];
#pragma unroll
  for (int t = 0; t < 36; t++) {
    float f = wff[t];
#pragma unroll
    for (int q = 0; q < 8; q++)
      t1v[q] += tbl[152 + t * 8 + q] * f;
  }

  // ---- layer 1 attention ----
  float wf1f[36];
#pragma unroll
  for (int h = 0; h < 4; h++) {
    float la[2], lo[2];
#pragma unroll
    for (int k2 = 0; k2 < 2; k2++) {
      float da = t1v[h*2][0]*nb[k2][0] + t1v[h*2][1]*nb[k2][1] + t1v[h*2][2]*nb[k2][2]
               + t1v[h*2][3]*nb[k2][3] + t1v[h*2+1][0]*nb[k2][4] + t1v[h*2+1][1]*nb[k2][5];
      la[k2] = da * dwa1[k2];
      float dof = t1v[h*2+1][2]*obf[k2][0] + t1v[h*2+1][3]*obf[k2][1];
      lo[k2] = dof * dwo1[k2];
    }
    float e  = __expf(la[1] - la[0]); float aa1 = e  / (1.f + e);  float aa0 = 1.f - aa1;
    float eo = __expf(lo[1] - lo[0]); float bo1 = eo / (1.f + eo); float bo0 = 1.f - bo1;
#pragma unroll
    for (int i = 0; i < 6; i++) wf1f[h * 9 + i] = aa0 * nb[0][i] + aa1 * nb[1][i];
    wf1f[h * 9 + 6] = aa0 * nbv6[0] + aa1 * nbv6[1];
    wf1f[h * 9 + 7] = bo0 * obf[0][0] + bo1 * obf[1][0];
    wf1f[h * 9 + 8] = bo0 * obf[0][1] + bo1 * obf[1][1];
  }

  // ---- output: B1H + wf1f @ AO1 (packed) ----
  v4f acc = tbl[484];
#pragma unroll
  for (int t = 0; t < 36; t++)
    acc += tbl[448 + t] * wf1f[t];
  ((v4f*)out)[gid] = acc;
}

extern "C" void kernel_launch(void* const* d_in, const int* in_sizes, int n_in,
                              void* d_out, int out_size, void* d_ws, size_t ws_size,
                              hipStream_t stream)
{
  const float* obs  = (const float*)d_in[0];
  const float* wq0  = (const float*)d_in[1];
  const float* wak0 = (const float*)d_in[2];
  const float* wav0 = (const float*)d_in[3];
  const float* wok0 = (const float*)d_in[4];
  const float* wov0 = (const float*)d_in[5];
  const float* apw0 = (const float*)d_in[6];
  const float* apb0 = (const float*)d_in[7];
  const float* opw0 = (const float*)d_in[8];
  const float* opb0 = (const float*)d_in[9];
  const float* fpw0 = (const float*)d_in[10];
  const float* fpb0 = (const float*)d_in[11];
  const float* ca0  = (const float*)d_in[12];
  const float* co0  = (const float*)d_in[13];
  const float* wq1  = (const float*)d_in[14];
  const float* wak1 = (const float*)d_in[15];
  const float* wav1 = (const float*)d_in[16];
  const float* wok1 = (const float*)d_in[17];
  const float* wov1 = (const float*)d_in[18];
  const float* apw1 = (const float*)d_in[19];
  const float* apb1 = (const float*)d_in[20];
  const float* opw1 = (const float*)d_in[21];
  const float* opb1 = (const float*)d_in[22];
  const float* fpw1 = (const float*)d_in[23];
  const float* fpb1 = (const float*)d_in[24];
  const float* ca1  = (const float*)d_in[25];
  const float* co1  = (const float*)d_in[26];
  const float* headw = (const float*)d_in[27];
  const float* headb = (const float*)d_in[28];
  float* ws = (float*)d_ws;
  int n = in_sizes[0] / 37;

  prep_fused<<<512, NTH, 0, stream>>>(
      wq0, wak0, wok0, wav0, wov0, apw0, opw0, fpw0, fpb0, apb0, opb0,
      wq1, wak1, wok1, wav1, wov1, apw1, opw1, fpw1, fpb1, apb1, opb1,
      headw, headb, obs, ws, n);
  actor_main<<<(n + NTH - 1) / NTH, NTH, 0, stream>>>(
      obs, ws, ca0, co0, ca1, co1, (float*)d_out, n);
}

// Round 2
// 150.588 us; speedup vs baseline: 1.1571x; 1.1571x over previous
//
#include <hip/hip_runtime.h>
#include <math.h>

#define NTH 256

typedef float v4f __attribute__((ext_vector_type(4)));

// ============ workspace float offsets ============
// Final tables (read wave-uniform by actor_main): 1940 floats = 485 float4
// (WQ0 / M / TB pre-scaled by 1/sqrt(32) — actor logits skip the scale mul)
enum : int {
  WQ0_OFF = 0,        // [4][19][8]  = 608
  M_OFF   = 608,      // [36][32]    = 1152   (AO0 @ WQ1fold, pre-scaled)
  TB_OFF  = 1760,     // [4][8]      = 32     (B0 @ WQ1fold, pre-scaled)
  AO1_OFF = 1792,     // [36][4]     = 144
  B1H_OFF = 1936,     // [4]         = 4
  // intermediates (prepA -> prepB), all 16B-aligned for v4f access
  PA0_OFF  = 2048,    // [4][7][128] = 3584
  PO0_OFF  = 5632,    // [4][2][128] = 1024
  PA1_OFF  = 6656,    // 3584
  PO1_OFF  = 10240,   // 1024
  WQ1T_OFF = 11264,   // [4][8][128] = 4096   (transposed fold: [h][j][cc])
  B0_OFF   = 15360,   // 128
  BB1_OFF  = 15488,   // 128
  HWT_OFF  = 15616,   // [4][128] = 512       (headw transposed)
  WS_END   = 16128
};

// ---------------- prepA: all independent tables, latency-optimized ----------------
// Every thread computes a float4 of outputs via coalesced v4f loads, fully
// unrolled so ~32 loads are in flight per waitcnt (cold-HBM latency paid once,
// not 32x).  Blocks: 0..8 P tables | 9..24 WQ1T | 25..27 WQ0 | 28 B0/BB1 | 29 headwT
__global__ __launch_bounds__(NTH) void prepA(
    const float* __restrict__ wq0,  const float* __restrict__ wak0, const float* __restrict__ wok0,
    const float* __restrict__ wav0, const float* __restrict__ wov0,
    const float* __restrict__ apw0, const float* __restrict__ opw0,
    const float* __restrict__ wq1,  const float* __restrict__ wak1, const float* __restrict__ wok1,
    const float* __restrict__ wav1, const float* __restrict__ wov1,
    const float* __restrict__ apw1, const float* __restrict__ opw1,
    const float* __restrict__ fpw0, const float* __restrict__ fpw1,
    const float* __restrict__ fpb0, const float* __restrict__ apb0, const float* __restrict__ opb0,
    const float* __restrict__ fpb1, const float* __restrict__ apb1, const float* __restrict__ opb1,
    const float* __restrict__ headw, float* __restrict__ ws)
{
  const int b = blockIdx.x;
  const int tid = threadIdx.x;
  const float scale = 0.17677669529663687f;   // 1/sqrt(32)

  if (b < 9) {
    // ---- P tables: P[h][i][t4] = sum_c w[c] * pw4[c*32 + t4]  (2304 v4f outputs)
    const int idx = b * NTH + tid;
    const float* w; const v4f* p4; int t4, outv;
    if (idx < 896) {
      int h = idx / 224, r = idx % 224, i = r >> 5; t4 = r & 31;
      w = wav0 + i * 512 + h * 128; p4 = (const v4f*)(apw0 + h * 16384);
      outv = (PA0_OFF >> 2) + (h * 7 + i) * 32 + t4;
    } else if (idx < 1152) {
      int k = idx - 896; int h = k >> 6, i = (k >> 5) & 1; t4 = k & 31;
      w = wov0 + i * 512 + h * 128; p4 = (const v4f*)(opw0 + h * 16384);
      outv = (PO0_OFF >> 2) + (h * 2 + i) * 32 + t4;
    } else if (idx < 2048) {
      int k = idx - 1152; int h = k / 224, r = k % 224, i = r >> 5; t4 = r & 31;
      w = wav1 + i * 512 + h * 128; p4 = (const v4f*)(apw1 + h * 16384);
      outv = (PA1_OFF >> 2) + (h * 7 + i) * 32 + t4;
    } else {
      int k = idx - 2048; int h = k >> 6, i = (k >> 5) & 1; t4 = k & 31;
      w = wov1 + i * 512 + h * 128; p4 = (const v4f*)(opw1 + h * 16384);
      outv = (PO1_OFF >> 2) + (h * 2 + i) * 32 + t4;
    }
    v4f acc = (v4f)0.f;
#pragma unroll 32
    for (int c = 0; c < 128; ++c) acc += w[c] * p4[c * 32 + t4];
    ((v4f*)ws)[outv] = acc;
  } else if (b < 25) {
    // ---- WQ1T[h][j][cc]: contiguous-c dot of wq1 row x wb1 row (4096 scalars)
    const int idx = (b - 9) * NTH + tid;
    const int cc = idx & 127, j = (idx >> 7) & 7, h = idx >> 10;
    const v4f* a4 = (const v4f*)(wq1 + cc * 512 + h * 128);
    const v4f* b4 = (const v4f*)(((j < 6) ? wak1 + j * 512 : wok1 + (j - 6) * 512) + h * 128);
    v4f s = (v4f)0.f;
#pragma unroll 16
    for (int c4 = 0; c4 < 32; ++c4) s += a4[c4] * b4[c4];
    ws[WQ1T_OFF + (h * 8 + j) * 128 + cc] = s[0] + s[1] + s[2] + s[3];
  } else if (b < 28) {
    // ---- WQ0[h][r][j] (608 scalars, pre-scaled)
    const int idx = (b - 25) * NTH + tid;
    if (idx < 608) {
      const int j = idx & 7, r = (idx >> 3) % 19, h = idx / 152;
      const v4f* a4 = (const v4f*)(wq0 + r * 512 + h * 128);
      const v4f* b4 = (const v4f*)(((j < 6) ? wak0 + j * 512 : wok0 + (j - 6) * 512) + h * 128);
      v4f s = (v4f)0.f;
#pragma unroll 16
      for (int c4 = 0; c4 < 32; ++c4) s += a4[c4] * b4[c4];
      ws[WQ0_OFF + idx] = (s[0] + s[1] + s[2] + s[3]) * scale;
    }
  } else if (b == 28) {
    // ---- B0[128] & BB1[128]: 4-way K-split + LDS reduce
    __shared__ v4f red[256];
    const int isB1 = tid >> 7;                 // 0: B0, 1: BB1
    const int s = tid & 127, j4 = s & 31, g = s >> 5;   // g in 0..3
    const v4f* fp4 = (const v4f*)(isB1 ? fpw1 : fpw0);
    const float* ab = isB1 ? apb1 : apb0;
    const float* ob = isB1 ? opb1 : opb0;
    const v4f* fb4 = (const v4f*)(isB1 ? fpb1 : fpb0);
    v4f acc = (v4f)0.f;
#pragma unroll 32
    for (int c = g * 32; c < g * 32 + 32; ++c)
      acc += ab[c] * fp4[c * 32 + j4] + ob[c] * fp4[(128 + c) * 32 + j4];
    red[tid] = acc;
    __syncthreads();
    if (g == 0) {
      v4f r = red[tid] + red[tid + 32] + red[tid + 64] + red[tid + 96] + fb4[j4];
      ((v4f*)(ws + (isB1 ? BB1_OFF : B0_OFF)))[j4] = r;
    }
  } else {
    // ---- headwT[o][c] = headw[c*4+o]  (512)
    for (int e = tid; e < 512; e += NTH) {
      const int o = e >> 7, c = e & 127;
      ws[HWT_OFF + e] = headw[c * 4 + o];
    }
  }
}

// ---------------- prepB: the chained tables (reads prepA's hot workspace) ----------------
// Blocks 0..35: M row t  (AO0 via 8-way split-K, then M via WQ1T contiguous dots)
// Blocks 36..71: AO1 row (R via 8-way split-K, then AO1 via headwT)
// Block 72: TB + B1H (all inputs L2/L3-hot)
__global__ __launch_bounds__(NTH) void prepB(
    const float* __restrict__ fpw0, const float* __restrict__ fpw1,
    const float* __restrict__ headb, float* __restrict__ ws)
{
  const int b = blockIdx.x;
  const int tid = threadIdx.x;
  const float scale = 0.17677669529663687f;
  __shared__ v4f sred[256];
  __shared__ float sV[128];

  if (b < 72) {
    const int isL1 = (b >= 36) ? 1 : 0;
    const int t = isL1 ? b - 36 : b;
    const int h = t / 9, i = t % 9;
    // phase 1: row vec (AO0 or R) via 8-way K-split, single latency round
    const int x4 = tid & 31, g = tid >> 5;     // g in 0..7
    const float* P = ws + (i < 7
        ? (isL1 ? PA1_OFF : PA0_OFF) + (h * 7 + i) * 128
        : (isL1 ? PO1_OFF : PO0_OFF) + (h * 2 + (i - 7)) * 128);
    const v4f* f4 = (const v4f*)((isL1 ? fpw1 : fpw0) + (i < 7 ? 0 : 16384));
    v4f acc = (v4f)0.f;
#pragma unroll
    for (int u = g * 16; u < g * 16 + 16; ++u) acc += P[u] * f4[u * 32 + x4];
    sred[tid] = acc;
    __syncthreads();
    if (g == 0) {
      v4f r = sred[x4];
#pragma unroll
      for (int q = 1; q < 8; ++q) r += sred[q * 32 + x4];
      ((v4f*)sV)[x4] = r;
    }
    __syncthreads();
    if (!isL1) {
      // phase 2: M[t][h2*8+j2] = scale * <sV, WQ1T[h2][j2][:]>
      if (tid < 32) {
        const int h2 = tid >> 3, j2 = tid & 7;
        const v4f* W4 = (const v4f*)(ws + WQ1T_OFF + (h2 * 8 + j2) * 128);
        const v4f* A4 = (const v4f*)sV;
        v4f a = (v4f)0.f;
#pragma unroll
        for (int c4 = 0; c4 < 32; ++c4) a += A4[c4] * W4[c4];
        ws[M_OFF + t * 32 + tid] = (a[0] + a[1] + a[2] + a[3]) * scale;
      }
    } else {
      // phase 2: AO1[t][o] = <sV, headwT[o][:]>
      if (tid < 4) {
        const v4f* H4 = (const v4f*)(ws + HWT_OFF + tid * 128);
        const v4f* R4 = (const v4f*)sV;
        v4f a = (v4f)0.f;
#pragma unroll
        for (int c4 = 0; c4 < 32; ++c4) a += R4[c4] * H4[c4];
        ws[AO1_OFF + t * 4 + tid] = a[0] + a[1] + a[2] + a[3];
      }
    }
  } else {
    // ---- TB[h][j] and B1H[o], all from hot workspace
    if (tid < 32) {
      const int h = tid >> 3, j = tid & 7;
      const v4f* B4 = (const v4f*)(ws + B0_OFF);
      const v4f* W4 = (const v4f*)(ws + WQ1T_OFF + (h * 8 + j) * 128);
      v4f a = (v4f)0.f;
#pragma unroll
      for (int c4 = 0; c4 < 32; ++c4) a += B4[c4] * W4[c4];
      ws[TB_OFF + tid] = (a[0] + a[1] + a[2] + a[3]) * scale;
    } else if (tid < 36) {
      const int o = tid - 32;
      const v4f* B4 = (const v4f*)(ws + BB1_OFF);
      const v4f* H4 = (const v4f*)(ws + HWT_OFF + o * 128);
      v4f a = (v4f)0.f;
#pragma unroll
      for (int c4 = 0; c4 < 32; ++c4) a += B4[c4] * H4[c4];
      ws[B1H_OFF + o] = a[0] + a[1] + a[2] + a[3] + headb[o];
    }
  }
}

// ---------------- main: 1 thread/sample; coalesced obs via LDS stage ----------------
__global__ __launch_bounds__(NTH) void actor_main(
    const float* __restrict__ obs, const float* __restrict__ ws,
    const float* __restrict__ pca0, const float* __restrict__ pco0,
    const float* __restrict__ pca1, const float* __restrict__ pco1,
    float* __restrict__ out, int n)
{
  const int tid = threadIdx.x;
  const int gid = blockIdx.x * NTH + tid;

  // ---- coalesced stage: 2368 float4 per block (256*37 floats), then
  //      per-thread reads at stride 37 (37 mod 32 = 5, coprime -> conflict-free)
  __shared__ v4f sObsV[NTH * 37 / 4];
  float* sObs = (float*)sObsV;
  {
    const size_t total_f = (size_t)n * 37;
    const size_t v4base = (size_t)blockIdx.x * (NTH * 37 / 4);
    const v4f* src = (const v4f*)obs;
#pragma unroll
    for (int k = 0; k < 9; k++) {
      const size_t vi = v4base + k * NTH + tid;
      if (vi * 4 + 4 <= total_f) {
        sObsV[k * NTH + tid] = src[vi];
      } else {
#pragma unroll
        for (int e = 0; e < 4; e++) {
          const size_t f = vi * 4 + e;
          if (f < total_f) sObs[(k * NTH + tid) * 4 + e] = obs[f];
        }
      }
    }
    if (tid < 64) {
      const size_t vi = v4base + 9 * NTH + tid;
      if (vi * 4 + 4 <= total_f) {
        sObsV[9 * NTH + tid] = src[vi];
      } else {
#pragma unroll
        for (int e = 0; e < 4; e++) {
          const size_t f = vi * 4 + e;
          if (f < total_f) sObs[(9 * NTH + tid) * 4 + e] = obs[f];
        }
      }
    }
  }
  __syncthreads();
  if (gid >= n) return;

  // All tbl[] indices below are compile-time constants -> wave-uniform
  // addresses -> scalar-pipe s_load; table (7.8 KB) stays K$-resident.
  const v4f* __restrict__ tbl = (const v4f*)ws;

  // ---- per-lane obs from LDS ----
  float o[37];
#pragma unroll
  for (int i = 0; i < 37; i++) o[i] = sObs[tid * 37 + i];

  // ---- unpack features ----
  float qf[19];
#pragma unroll
  for (int i = 0; i < 12; i++) qf[i] = o[i];
#pragma unroll
  for (int i = 0; i < 7; i++) qf[12 + i] = o[30 + i];
  float nb[2][6];
#pragma unroll
  for (int k2 = 0; k2 < 2; k2++)
#pragma unroll
    for (int i = 0; i < 6; i++) nb[k2][i] = o[12 + 6 * k2 + i];
  const float nbv6[2] = { o[24], o[25] };
  const float obf[2][2] = { { o[26], o[27] }, { o[28], o[29] } };
  const float ax = o[0], ay = o[1];

  // ---- distances & decay weights ----
  float dista[2], disto[2];
#pragma unroll
  for (int k2 = 0; k2 < 2; k2++) {
    float dx = ax - nb[k2][0], dy = ay - nb[k2][1];
    dista[k2] = sqrtf(dx * dx + dy * dy);
    float ex = ax - obf[k2][0], ey = ay - obf[k2][1];
    disto[k2] = sqrtf(ex * ex + ey * ey);
  }
  const float ca0 = pca0[0], co0 = pco0[0], ca1 = pca1[0], co1 = pco1[0];
  float dwa0[2], dwo0[2], dwa1[2], dwo1[2];
#pragma unroll
  for (int k2 = 0; k2 < 2; k2++) {
    dwa0[k2] = __expf(-ca0 * dista[k2]);
    dwo0[k2] = __expf(-co0 * disto[k2]);
    dwa1[k2] = __expf(-ca1 * dista[k2]);
    dwo1[k2] = __expf(-co1 * disto[k2]);
  }

  // ---- layer 0 query fold: t0v[h*2+half] (packed, pre-scaled tables) ----
  v4f t0v[8];
#pragma unroll
  for (int z = 0; z < 8; z++) t0v[z] = (v4f)0.f;
#pragma unroll
  for (int h = 0; h < 4; h++) {
#pragma unroll
    for (int r = 0; r < 19; r++) {
      float q = qf[r];
      t0v[h * 2 + 0] += tbl[(h * 19 + r) * 2 + 0] * q;
      t0v[h * 2 + 1] += tbl[(h * 19 + r) * 2 + 1] * q;
    }
  }

  // ---- layer 0 attention -> weighted features wff[36] (t = h*9+i) ----
  float wff[36];
#pragma unroll
  for (int h = 0; h < 4; h++) {
    float la[2], lo[2];
#pragma unroll
    for (int k2 = 0; k2 < 2; k2++) {
      float da = t0v[h*2][0]*nb[k2][0] + t0v[h*2][1]*nb[k2][1] + t0v[h*2][2]*nb[k2][2]
               + t0v[h*2][3]*nb[k2][3] + t0v[h*2+1][0]*nb[k2][4] + t0v[h*2+1][1]*nb[k2][5];
      la[k2] = da * dwa0[k2];
      float dof = t0v[h*2+1][2]*obf[k2][0] + t0v[h*2+1][3]*obf[k2][1];
      lo[k2] = dof * dwo0[k2];
    }
    float e  = __expf(la[1] - la[0]); float aa1 = e  / (1.f + e);  float aa0 = 1.f - aa1;
    float eo = __expf(lo[1] - lo[0]); float bo1 = eo / (1.f + eo); float bo0 = 1.f - bo1;
#pragma unroll
    for (int i = 0; i < 6; i++) wff[h * 9 + i] = aa0 * nb[0][i] + aa1 * nb[1][i];
    wff[h * 9 + 6] = aa0 * nbv6[0] + aa1 * nbv6[1];
    wff[h * 9 + 7] = bo0 * obf[0][0] + bo1 * obf[1][0];
    wff[h * 9 + 8] = bo0 * obf[0][1] + bo1 * obf[1][1];
  }

  // ---- layer 1 query fold via M: t1v = TB + wff @ M (packed, pre-scaled) ----
  v4f t1v[8];
#pragma unroll
  for (int q = 0; q < 8; q++) t1v[q] = tbl[440 + q];
#pragma unroll
  for (int t = 0; t < 36; t++) {
    float f = wff[t];
#pragma unroll
    for (int q = 0; q < 8; q++)
      t1v[q] += tbl[152 + t * 8 + q] * f;
  }

  // ---- layer 1 attention ----
  float wf1f[36];
#pragma unroll
  for (int h = 0; h < 4; h++) {
    float la[2], lo[2];
#pragma unroll
    for (int k2 = 0; k2 < 2; k2++) {
      float da = t1v[h*2][0]*nb[k2][0] + t1v[h*2][1]*nb[k2][1] + t1v[h*2][2]*nb[k2][2]
               + t1v[h*2][3]*nb[k2][3] + t1v[h*2+1][0]*nb[k2][4] + t1v[h*2+1][1]*nb[k2][5];
      la[k2] = da * dwa1[k2];
      float dof = t1v[h*2+1][2]*obf[k2][0] + t1v[h*2+1][3]*obf[k2][1];
      lo[k2] = dof * dwo1[k2];
    }
    float e  = __expf(la[1] - la[0]); float aa1 = e  / (1.f + e);  float aa0 = 1.f - aa1;
    float eo = __expf(lo[1] - lo[0]); float bo1 = eo / (1.f + eo); float bo0 = 1.f - bo1;
#pragma unroll
    for (int i = 0; i < 6; i++) wf1f[h * 9 + i] = aa0 * nb[0][i] + aa1 * nb[1][i];
    wf1f[h * 9 + 6] = aa0 * nbv6[0] + aa1 * nbv6[1];
    wf1f[h * 9 + 7] = bo0 * obf[0][0] + bo1 * obf[1][0];
    wf1f[h * 9 + 8] = bo0 * obf[0][1] + bo1 * obf[1][1];
  }

  // ---- output: B1H + wf1f @ AO1 (packed) ----
  v4f acc = tbl[484];
#pragma unroll
  for (int t = 0; t < 36; t++)
    acc += tbl[448 + t] * wf1f[t];
  ((v4f*)out)[gid] = acc;
}

extern "C" void kernel_launch(void* const* d_in, const int* in_sizes, int n_in,
                              void* d_out, int out_size, void* d_ws, size_t ws_size,
                              hipStream_t stream)
{
  const float* obs  = (const float*)d_in[0];
  const float* wq0  = (const float*)d_in[1];
  const float* wak0 = (const float*)d_in[2];
  const float* wav0 = (const float*)d_in[3];
  const float* wok0 = (const float*)d_in[4];
  const float* wov0 = (const float*)d_in[5];
  const float* apw0 = (const float*)d_in[6];
  const float* apb0 = (const float*)d_in[7];
  const float* opw0 = (const float*)d_in[8];
  const float* opb0 = (const float*)d_in[9];
  const float* fpw0 = (const float*)d_in[10];
  const float* fpb0 = (const float*)d_in[11];
  const float* ca0  = (const float*)d_in[12];
  const float* co0  = (const float*)d_in[13];
  const float* wq1  = (const float*)d_in[14];
  const float* wak1 = (const float*)d_in[15];
  const float* wav1 = (const float*)d_in[16];
  const float* wok1 = (const float*)d_in[17];
  const float* wov1 = (const float*)d_in[18];
  const float* apw1 = (const float*)d_in[19];
  const float* apb1 = (const float*)d_in[20];
  const float* opw1 = (const float*)d_in[21];
  const float* opb1 = (const float*)d_in[22];
  const float* fpw1 = (const float*)d_in[23];
  const float* fpb1 = (const float*)d_in[24];
  const float* ca1  = (const float*)d_in[25];
  const float* co1  = (const float*)d_in[26];
  const float* headw = (const float*)d_in[27];
  const float* headb = (const float*)d_in[28];
  float* ws = (float*)d_ws;
  int n = in_sizes[0] / 37;

  prepA<<<30, NTH, 0, stream>>>(
      wq0, wak0, wok0, wav0, wov0, apw0, opw0,
      wq1, wak1, wok1, wav1, wov1, apw1, opw1,
      fpw0, fpw1, fpb0, apb0, opb0, fpb1, apb1, opb1, headw, ws);
  prepB<<<73, NTH, 0, stream>>>(fpw0, fpw1, headb, ws);
  actor_main<<<(n + NTH - 1) / NTH, NTH, 0, stream>>>(
      obs, ws, ca0, co0, ca1, co1, (float*)d_out, n);
}